// Round 7
// baseline (321.657 us; speedup 1.0000x reference)
//
#include <hip/hip_runtime.h>

#define FEAT 128
#define HID 32
#define EMB 16
#define NEG 0.2f

// CSR-build binning parameters. Assumes Nn <= 2^17 (src id fits 17 bits) and
// Nn <= NBMAX*BIN_NODES. For this problem Nn=100000, E=3.2M.
#define BSH 8                 // 256 nodes per bin
#define BIN_NODES 256
#define NBMAX 400             // >= ceil(100000/256)=391
#define CH 8192               // edges per partition block
#define CAP 12288             // LDS staging capacity per bin (mean 8192, +45 sigma)
#define SRCBITS 17
#define SRCMASK 0x1FFFF

__device__ __forceinline__ float lrelu(float a) { return a > 0.0f ? a : NEG * a; }

__global__ __launch_bounds__(256) void k_zero_int(int* p, int n) {
    int i = (int)(blockIdx.x * 256 + threadIdx.x);
    if (i < n) p[i] = 0;
}

// ---- CSR build, phase 1: per-bin edge counts (dst >> BSH) ----
__global__ __launch_bounds__(256) void k_bincnt(const int* __restrict__ ei, int E_,
                                                int Nn, int* __restrict__ binCnt) {
    __shared__ int h[NBMAX];
    int nb = (Nn + BIN_NODES - 1) >> BSH;
    for (int i = threadIdx.x; i < nb; i += 256) h[i] = 0;
    __syncthreads();
    int stride = (int)(gridDim.x * 256);
    for (int i = (int)(blockIdx.x * 256 + threadIdx.x); i < E_; i += stride)
        atomicAdd(&h[ei[(size_t)E_ + i] >> BSH], 1);
    __syncthreads();
    for (int i = threadIdx.x; i < nb; i += 256)
        if (h[i]) atomicAdd(&binCnt[i], h[i]);
}

// ---- phase 2: scan bin counts -> binstart, init bin_pos; rowptr[Nn]=E ----
__global__ __launch_bounds__(512) void k_binscan(const int* __restrict__ binCnt,
                                                 int* __restrict__ binstart,
                                                 int* __restrict__ bin_pos,
                                                 int* __restrict__ rowptr,
                                                 int Nn, int E_) {
    __shared__ int s[512];
    int nb = (Nn + BIN_NODES - 1) >> BSH;
    int t = (int)threadIdx.x;
    s[t] = (t < nb) ? binCnt[t] : 0;
    __syncthreads();
    for (int off = 1; off < 512; off <<= 1) {
        int v = (t >= off) ? s[t - off] : 0;
        __syncthreads();
        s[t] += v;
        __syncthreads();
    }
    if (t <= nb) binstart[t] = (t == 0) ? 0 : s[t - 1];
    if (t < nb) bin_pos[t] = (t == 0) ? 0 : s[t - 1];
    if (t == 0) rowptr[Nn] = E_;
}

// ---- phase 3: multisplit partition. Stage chunk in LDS grouped by bin, then
// write contiguous per-bin runs of packed words ((dst&255)<<17 | src). ----
__global__ __launch_bounds__(1024) void k_part(const int* __restrict__ ei, int E_,
                                               int Nn, int* __restrict__ bin_pos,
                                               int* __restrict__ packed) {
    __shared__ int hist[NBMAX];
    __shared__ int lofs[NBMAX];
    __shared__ int pos[NBMAX];
    __shared__ int gbase[NBMAX];
    __shared__ int sscan[512];
    __shared__ int staged[CH];
    __shared__ unsigned short sbin[CH];
    int nb = (Nn + BIN_NODES - 1) >> BSH;
    int base = (int)(blockIdx.x * CH);
    int nE = min(CH, E_ - base);
    int t = (int)threadIdx.x;
    for (int i = t; i < nb; i += 1024) hist[i] = 0;
    __syncthreads();

    int myw[CH / 1024];
    int myb[CH / 1024];
#pragma unroll
    for (int k = 0; k < CH / 1024; ++k) {
        int i = t + k * 1024;
        int w = 0, b_ = -1;
        if (i < nE) {
            int s_ = ei[base + i];
            int d_ = ei[(size_t)E_ + base + i];
            b_ = d_ >> BSH;
            w = ((d_ & (BIN_NODES - 1)) << SRCBITS) | s_;
            atomicAdd(&hist[b_], 1);
        }
        myw[k] = w;
        myb[k] = b_;
    }
    __syncthreads();
    // exclusive scan of hist over 512-wide region
    if (t < 512) sscan[t] = (t < nb) ? hist[t] : 0;
    __syncthreads();
    for (int off = 1; off < 512; off <<= 1) {
        int v = 0;
        if (t < 512 && t >= off) v = sscan[t - off];
        __syncthreads();
        if (t < 512) sscan[t] += v;
        __syncthreads();
    }
    for (int i = t; i < nb; i += 1024) {
        int ex = (i == 0) ? 0 : sscan[i - 1];
        lofs[i] = ex;
        pos[i] = ex;
    }
    __syncthreads();
    // scatter into LDS grouped by bin
#pragma unroll
    for (int k = 0; k < CH / 1024; ++k) {
        if (myb[k] >= 0) {
            int p = atomicAdd(&pos[myb[k]], 1);
            staged[p] = myw[k];
            sbin[p] = (unsigned short)myb[k];
        }
    }
    __syncthreads();
    // reserve global runs (one atomic per non-empty bin)
    for (int i = t; i < nb; i += 1024)
        gbase[i] = hist[i] ? atomicAdd(&bin_pos[i], hist[i]) : 0;
    __syncthreads();
    // coalesced write-out of per-bin runs
    for (int i = t; i < nE; i += 1024) {
        int b_ = sbin[i];
        packed[gbase[b_] + (i - lofs[b_])] = staged[i];
    }
}

// ---- phase 4: per-bin build. LDS scatter -> coalesced CSR (in place over
// packed), and writes the bin's slice of rowptr. scratch = h1 buffer (free
// until k_h1 runs) used only in the (statistically impossible) overflow path.
__global__ __launch_bounds__(1024) void k_build(const int* __restrict__ binstart,
                                                int Nn, int E_,
                                                int* __restrict__ packed,
                                                int* __restrict__ rowptr,
                                                int* __restrict__ scratch) {
    __shared__ int ncnt[BIN_NODES];
    __shared__ int npos[BIN_NODES];
    __shared__ int sscan[BIN_NODES];
    __shared__ int csr_l[CAP];
    int b = (int)blockIdx.x;
    int s = binstart[b], e = binstart[b + 1];
    int cnt = e - s;
    int nb0 = b << BSH;
    int nodes = min(BIN_NODES, Nn - nb0);
    int t = (int)threadIdx.x;
    if (t < BIN_NODES) ncnt[t] = 0;
    __syncthreads();
    for (int i = t; i < cnt; i += 1024) atomicAdd(&ncnt[packed[s + i] >> SRCBITS], 1);
    __syncthreads();
    if (t < BIN_NODES) sscan[t] = ncnt[t];
    __syncthreads();
    for (int off = 1; off < BIN_NODES; off <<= 1) {
        int v = 0;
        if (t < BIN_NODES && t >= off) v = sscan[t - off];
        __syncthreads();
        if (t < BIN_NODES) sscan[t] += v;
        __syncthreads();
    }
    if (t < BIN_NODES) {
        int ex = (t == 0) ? 0 : sscan[t - 1];
        npos[t] = ex;
        if (t < nodes) rowptr[nb0 + t] = s + ex;
    }
    __syncthreads();
    if (cnt <= CAP) {
        for (int i = t; i < cnt; i += 1024) {
            int w = packed[s + i];
            int p = atomicAdd(&npos[w >> SRCBITS], 1);
            csr_l[p] = w & SRCMASK;
        }
        __syncthreads();
        for (int i = t; i < cnt; i += 1024) packed[s + i] = csr_l[i];
    } else {
        // overflow fallback: stage via global scratch, then in-place scatter
        for (int i = t; i < cnt; i += 1024) scratch[s + i] = packed[s + i];
        __syncthreads();
        for (int i = t; i < cnt; i += 1024) {
            int w = scratch[s + i];
            int p = atomicAdd(&npos[w >> SRCBITS], 1);
            packed[s + p] = w & SRCMASK;
        }
    }
}

// h1 = x @ W1 ; als/ald.  ONE ROW PER THREAD. x loads are per-lane float4 of
// the lane's own row (all bytes consumed by the wave within 4 iters, L2-hot).
// W1 accesses are wave-uniform -> compiler scalarizes to s_load, inner loop
// becomes v_fmac(v_acc, s_w, v_x): no LDS, no shuffles, no syncthreads.
__global__ __launch_bounds__(256) void k_h1(
    const float* __restrict__ x, const float* __restrict__ W1,
    const float* __restrict__ a_s, const float* __restrict__ a_d,
    float* __restrict__ h1, float* __restrict__ als, float* __restrict__ ald, int Nn)
{
    int row = (int)(blockIdx.x * 256 + threadIdx.x);
    if (row >= Nn) return;
    const float4* xr = (const float4*)(x + (size_t)row * FEAT);
    float acc[HID];
#pragma unroll
    for (int c = 0; c < HID; ++c) acc[c] = 0.0f;
#pragma unroll 4
    for (int k4 = 0; k4 < FEAT / 4; ++k4) {
        float4 xv = xr[k4];
        const float* Wr = W1 + k4 * 4 * HID;   // wave-uniform -> s_load
#pragma unroll
        for (int c = 0; c < HID; ++c)
            acc[c] += xv.x * Wr[c] + xv.y * Wr[HID + c]
                    + xv.z * Wr[2 * HID + c] + xv.w * Wr[3 * HID + c];
    }
    float4* hr = (float4*)(h1 + (size_t)row * HID);
    float ps = 0.0f, pd = 0.0f;
#pragma unroll
    for (int c4 = 0; c4 < HID / 4; ++c4) {
        float4 hv;
        hv.x = acc[4 * c4 + 0]; hv.y = acc[4 * c4 + 1];
        hv.z = acc[4 * c4 + 2]; hv.w = acc[4 * c4 + 3];
        hr[c4] = hv;
        ps += hv.x * a_s[4 * c4 + 0] + hv.y * a_s[4 * c4 + 1]
            + hv.z * a_s[4 * c4 + 2] + hv.w * a_s[4 * c4 + 3];
        pd += hv.x * a_d[4 * c4 + 0] + hv.y * a_d[4 * c4 + 1]
            + hv.z * a_d[4 * c4 + 2] + hv.w * a_d[4 * c4 + 3];
    }
    als[row] = ps;
    ald[row] = pd;
}

// layer-1 gather-aggregate + norm + relu + (g @ W2) + als2/ald2, fused.
// 8 lanes per node, each lane owns 4 features (float4, 16 B/lane). Edge loop
// unrolled 4x: four independent 128 B row-gathers in flight per group; edge
// weights redundant per lane (8x, identical across group -> no reduction).
__global__ __launch_bounds__(256) void k_agg1(
    const int* __restrict__ rowptr, const int* __restrict__ csr_src,
    const float* __restrict__ h1, const float* __restrict__ als,
    const float* __restrict__ ald, const float* __restrict__ b1,
    const float* __restrict__ W2, const float* __restrict__ a_s2,
    const float* __restrict__ a_d2,
    float* __restrict__ h2, float* __restrict__ als2, float* __restrict__ ald2, int Nn)
{
    int n = (int)(blockIdx.x * 32 + (threadIdx.x >> 3));
    if (n >= Nn) return;
    int l = threadIdx.x & 7;                   // lane in 8-lane group
    const float4* h1p = (const float4*)h1;     // row s = elems [s*8 .. s*8+7]
    float aldn = ald[n];
    float wself = __expf(lrelu(als[n] + aldn));
    float4 sv = h1p[(size_t)n * 8 + l];
    float s0x = wself * sv.x, s0y = wself * sv.y;
    float s0z = wself * sv.z, s0w = wself * sv.w;
    float s1x = 0, s1y = 0, s1z = 0, s1w = 0;
    float s2x = 0, s2y = 0, s2z = 0, s2w = 0;
    float s3x = 0, s3y = 0, s3z = 0, s3w = 0;
    float den = wself;
    int e = rowptr[n], e1 = rowptr[n + 1];
    for (; e + 4 <= e1; e += 4) {
        int i0 = csr_src[e + 0];
        int i1 = csr_src[e + 1];
        int i2 = csr_src[e + 2];
        int i3 = csr_src[e + 3];
        float4 f0 = h1p[(size_t)i0 * 8 + l];
        float4 f1 = h1p[(size_t)i1 * 8 + l];
        float4 f2 = h1p[(size_t)i2 * 8 + l];
        float4 f3 = h1p[(size_t)i3 * 8 + l];
        float a0 = als[i0], a1 = als[i1], a2 = als[i2], a3 = als[i3];
        float w0 = __expf(lrelu(a0 + aldn));
        float w1 = __expf(lrelu(a1 + aldn));
        float w2 = __expf(lrelu(a2 + aldn));
        float w3 = __expf(lrelu(a3 + aldn));
        s0x += w0 * f0.x; s0y += w0 * f0.y; s0z += w0 * f0.z; s0w += w0 * f0.w;
        s1x += w1 * f1.x; s1y += w1 * f1.y; s1z += w1 * f1.z; s1w += w1 * f1.w;
        s2x += w2 * f2.x; s2y += w2 * f2.y; s2z += w2 * f2.z; s2w += w2 * f2.w;
        s3x += w3 * f3.x; s3y += w3 * f3.y; s3z += w3 * f3.z; s3w += w3 * f3.w;
        den += (w0 + w1) + (w2 + w3);
    }
    for (; e < e1; ++e) {
        int s = csr_src[e];
        float we = __expf(lrelu(als[s] + aldn));
        float4 f = h1p[(size_t)s * 8 + l];
        s0x += we * f.x; s0y += we * f.y; s0z += we * f.z; s0w += we * f.w;
        den += we;
    }
    float inv = 1.0f / den;
    float gx = fmaxf((s0x + s1x + s2x + s3x) * inv + b1[4 * l + 0], 0.0f);
    float gy = fmaxf((s0y + s1y + s2y + s3y) * inv + b1[4 * l + 1], 0.0f);
    float gz = fmaxf((s0z + s1z + s2z + s3z) * inv + b1[4 * l + 2], 0.0f);
    float gw = fmaxf((s0w + s1w + s2w + s3w) * inv + b1[4 * l + 3], 0.0f);
    // h2[n][j] = sum_t g[t] * W2[t][j]; lane l computes cols l and l+8.
    float hc0 = 0.0f, hc1 = 0.0f;
#pragma unroll
    for (int tt = 0; tt < 8; ++tt) {
        float bx = __shfl(gx, tt, 8);
        float by = __shfl(gy, tt, 8);
        float bz = __shfl(gz, tt, 8);
        float bw = __shfl(gw, tt, 8);
        const float* wp = &W2[(4 * tt) * EMB];
        hc0 += bx * wp[l] + by * wp[EMB + l]
             + bz * wp[2 * EMB + l] + bw * wp[3 * EMB + l];
        hc1 += bx * wp[l + 8] + by * wp[EMB + l + 8]
             + bz * wp[2 * EMB + l + 8] + bw * wp[3 * EMB + l + 8];
    }
    h2[(size_t)n * EMB + l] = hc0;
    h2[(size_t)n * EMB + l + 8] = hc1;
    float ps = hc0 * a_s2[l] + hc1 * a_s2[l + 8];
    float pd = hc0 * a_d2[l] + hc1 * a_d2[l + 8];
    for (int m = 1; m < 8; m <<= 1) {
        ps += __shfl_xor(ps, m, 8);
        pd += __shfl_xor(pd, m, 8);
    }
    if (l == 0) { als2[n] = ps; ald2[n] = pd; }
}

// layer-2 gather-aggregate + bias. 4 lanes per node, float4 features (row =
// 64 B = one cache line per gather group), 4x unrolled independent chains.
__global__ __launch_bounds__(256) void k_agg2(
    const int* __restrict__ rowptr, const int* __restrict__ csr_src,
    const float* __restrict__ h2, const float* __restrict__ als,
    const float* __restrict__ ald, const float* __restrict__ b2,
    float* __restrict__ out, int Nn)
{
    int n = (int)(blockIdx.x * 64 + (threadIdx.x >> 2));
    if (n >= Nn) return;
    int l = threadIdx.x & 3;                   // lane in 4-lane group
    const float4* h2p = (const float4*)h2;     // row s = elems [s*4 .. s*4+3]
    float aldn = ald[n];
    float wself = __expf(lrelu(als[n] + aldn));
    float4 sv = h2p[(size_t)n * 4 + l];
    float s0x = wself * sv.x, s0y = wself * sv.y;
    float s0z = wself * sv.z, s0w = wself * sv.w;
    float s1x = 0, s1y = 0, s1z = 0, s1w = 0;
    float s2x = 0, s2y = 0, s2z = 0, s2w = 0;
    float s3x = 0, s3y = 0, s3z = 0, s3w = 0;
    float den = wself;
    int e = rowptr[n], e1 = rowptr[n + 1];
    for (; e + 4 <= e1; e += 4) {
        int i0 = csr_src[e + 0];
        int i1 = csr_src[e + 1];
        int i2 = csr_src[e + 2];
        int i3 = csr_src[e + 3];
        float4 f0 = h2p[(size_t)i0 * 4 + l];
        float4 f1 = h2p[(size_t)i1 * 4 + l];
        float4 f2 = h2p[(size_t)i2 * 4 + l];
        float4 f3 = h2p[(size_t)i3 * 4 + l];
        float a0 = als[i0], a1 = als[i1], a2 = als[i2], a3 = als[i3];
        float w0 = __expf(lrelu(a0 + aldn));
        float w1 = __expf(lrelu(a1 + aldn));
        float w2 = __expf(lrelu(a2 + aldn));
        float w3 = __expf(lrelu(a3 + aldn));
        s0x += w0 * f0.x; s0y += w0 * f0.y; s0z += w0 * f0.z; s0w += w0 * f0.w;
        s1x += w1 * f1.x; s1y += w1 * f1.y; s1z += w1 * f1.z; s1w += w1 * f1.w;
        s2x += w2 * f2.x; s2y += w2 * f2.y; s2z += w2 * f2.z; s2w += w2 * f2.w;
        s3x += w3 * f3.x; s3y += w3 * f3.y; s3z += w3 * f3.z; s3w += w3 * f3.w;
        den += (w0 + w1) + (w2 + w3);
    }
    for (; e < e1; ++e) {
        int s = csr_src[e];
        float we = __expf(lrelu(als[s] + aldn));
        float4 f = h2p[(size_t)s * 4 + l];
        s0x += we * f.x; s0y += we * f.y; s0z += we * f.z; s0w += we * f.w;
        den += we;
    }
    float inv = 1.0f / den;
    float4 r;
    r.x = (s0x + s1x + s2x + s3x) * inv + b2[4 * l + 0];
    r.y = (s0y + s1y + s2y + s3y) * inv + b2[4 * l + 1];
    r.z = (s0z + s1z + s2z + s3z) * inv + b2[4 * l + 2];
    r.w = (s0w + s1w + s2w + s3w) * inv + b2[4 * l + 3];
    ((float4*)out)[(size_t)n * 4 + l] = r;
}

extern "C" void kernel_launch(void* const* d_in, const int* in_sizes, int n_in,
                              void* d_out, int out_size, void* d_ws, size_t ws_size,
                              hipStream_t stream)
{
    const float* x   = (const float*)d_in[0];
    const int*   ei  = (const int*)d_in[1];
    // d_in[2] = ew, unused (edge_dim=None)
    const float* W1  = (const float*)d_in[3];
    const float* as1 = (const float*)d_in[4];
    const float* ad1 = (const float*)d_in[5];
    const float* b1  = (const float*)d_in[6];
    const float* W2  = (const float*)d_in[7];
    const float* as2 = (const float*)d_in[8];
    const float* ad2 = (const float*)d_in[9];
    const float* b2  = (const float*)d_in[10];
    float* out = (float*)d_out;

    const int Nn = in_sizes[0] / FEAT;   // 100000
    const int E_ = in_sizes[1] / 2;      // 3200000
    const int nb = (Nn + BIN_NODES - 1) >> BSH;   // 391

    // workspace layout
    float* h1    = (float*)d_ws;                  // Nn*32 (also CSR-build scratch)
    float* als1  = h1 + (size_t)Nn * HID;         // Nn
    float* ald1  = als1 + Nn;                     // Nn
    float* h2    = ald1 + Nn;                     // Nn*16
    float* als2p = h2 + (size_t)Nn * EMB;         // Nn
    float* ald2p = als2p + Nn;                    // Nn
    int* rowptr  = (int*)(ald2p + Nn);            // Nn+1
    int* binCnt  = rowptr + Nn + 1;               // NBMAX
    int* binstart= binCnt + NBMAX;                // NBMAX+1
    int* bin_pos = binstart + NBMAX + 1;          // NBMAX
    int* packed  = bin_pos + NBMAX;               // E_  (becomes csr_src in place)
    // total: 52*Nn floats + (Nn+1+3*NBMAX+1+E_) ints ~= 34 MB

    // ---- build CSR (by destination) via binned counting sort ----
    k_zero_int<<<(nb + 255) / 256, 256, 0, stream>>>(binCnt, nb);
    k_bincnt<<<1024, 256, 0, stream>>>(ei, E_, Nn, binCnt);
    k_binscan<<<1, 512, 0, stream>>>(binCnt, binstart, bin_pos, rowptr, Nn, E_);
    k_part<<<(E_ + CH - 1) / CH, 1024, 0, stream>>>(ei, E_, Nn, bin_pos, packed);
    k_build<<<nb, 1024, 0, stream>>>(binstart, Nn, E_, packed, rowptr, (int*)h1);

    // ---- layer 1 ----
    k_h1<<<(Nn + 255) / 256, 256, 0, stream>>>(x, W1, as1, ad1, h1, als1, ald1, Nn);
    k_agg1<<<(Nn + 31) / 32, 256, 0, stream>>>(rowptr, packed, h1, als1, ald1,
                                               b1, W2, as2, ad2, h2, als2p, ald2p, Nn);
    // ---- layer 2 ----
    k_agg2<<<(Nn + 63) / 64, 256, 0, stream>>>(rowptr, packed, h2, als2p, ald2p,
                                               b2, out, Nn);
}